// Round 10
// baseline (272.919 us; speedup 1.0000x reference)
//
#include <hip/hip_runtime.h>
#include <math.h>

#define QN 8192
#define SN 32768
#define EN 131072
#define DN 256
#define HN 8
#define HDN 32
#define GEON 128
#define FFNN 512

typedef __attribute__((ext_vector_type(8))) short bf16x8;
typedef __attribute__((ext_vector_type(8))) unsigned short u16x8;
typedef __attribute__((ext_vector_type(4))) unsigned short u16x4;
typedef __attribute__((ext_vector_type(4))) float f32x4;

__device__ __forceinline__ unsigned short f2b(float f) {
  union { float f; unsigned u; } v; v.f = f;
  unsigned u = v.u;
  u += 0x7fffu + ((u >> 16) & 1u);   // round-to-nearest-even
  return (unsigned short)(u >> 16);
}
__device__ __forceinline__ float b2f(unsigned short h) {
  union { unsigned u; float f; } v; v.u = ((unsigned)h) << 16; return v.f;
}
__device__ __forceinline__ float gelu_f(float x) {
  return 0.5f * x * (1.0f + erff(x * 0.70710678118654752440f));
}

// ================= prep kernel: transpose(136) | seg_offsets(33) | LN1(2048) =================
#define TRB 136
#define SOB 33
__global__ __launch_bounds__(256) void prep_kernel(
    const float* Wq, const float* Wk, const float* Wv, const float* Wg,
    const float* Wo, const float* Wf1, const float* Wf2,
    unsigned short* WqT, unsigned short* WkvT, unsigned short* WgT,
    unsigned short* WoT, unsigned short* Wf1T, unsigned short* Wf2T,
    const int* q_idx, int* offs,
    const float* x, const float* g, const float* bln, unsigned short* qt_b) {
  __shared__ float ts[64][65];
  int b = blockIdx.x;
  int t = threadIdx.x;
  if (b < TRB) {
    const float* src; unsigned short* dst; int K, N, tile;
    if (b < 16)       { src = Wq;  dst = WqT;          K = 256; N = 256; tile = b; }
    else if (b < 32)  { src = Wk;  dst = WkvT;         K = 256; N = 256; tile = b - 16; }
    else if (b < 48)  { src = Wv;  dst = WkvT + 65536; K = 256; N = 256; tile = b - 32; }
    else if (b < 56)  { src = Wg;  dst = WgT;          K = 128; N = 256; tile = b - 48; }
    else if (b < 72)  { src = Wo;  dst = WoT;          K = 256; N = 256; tile = b - 56; }
    else if (b < 104) { src = Wf1; dst = Wf1T;         K = 256; N = 512; tile = b - 72; }
    else              { src = Wf2; dst = Wf2T;         K = 512; N = 256; tile = b - 104; }
    int ktiles = K >> 6;
    int k0 = (tile % ktiles) * 64, n0 = (tile / ktiles) * 64;
    int c4 = (t & 15) * 4;
    int r = t >> 4;
#pragma unroll
    for (int p = 0; p < 4; ++p) {
      int row = p * 16 + r;
      float4 v = *(const float4*)(src + (size_t)(k0 + row) * N + n0 + c4);
      ts[row][c4 + 0] = v.x; ts[row][c4 + 1] = v.y;
      ts[row][c4 + 2] = v.z; ts[row][c4 + 3] = v.w;
    }
    __syncthreads();
#pragma unroll
    for (int p = 0; p < 4; ++p) {
      int n = p * 16 + r;
      ushort4 o;
      o.x = f2b(ts[c4 + 0][n]); o.y = f2b(ts[c4 + 1][n]);
      o.z = f2b(ts[c4 + 2][n]); o.w = f2b(ts[c4 + 3][n]);
      *(ushort4*)(dst + (size_t)(n0 + n) * K + k0 + c4) = o;
    }
  } else if (b < TRB + SOB) {
    int i = (b - TRB) * 256 + t;
    if (i > QN) return;
    int lo = 0, hi = EN;
    while (lo < hi) {
      int mid = (lo + hi) >> 1;
      if (q_idx[mid] < i) lo = mid + 1; else hi = mid;
    }
    offs[i] = lo;
  } else {
    int row = (b - TRB - SOB) * 4 + (t >> 6);
    int lane = t & 63;
    const float* xr = x + (size_t)row * DN;
    float4 v = *(const float4*)(xr + lane * 4);
    float s = v.x + v.y + v.z + v.w;
    float ss = v.x * v.x + v.y * v.y + v.z * v.z + v.w * v.w;
#pragma unroll
    for (int msk = 1; msk <= 32; msk <<= 1) {
      s += __shfl_xor(s, msk);
      ss += __shfl_xor(ss, msk);
    }
    float mean = s * (1.f / 256.f);
    float var = ss * (1.f / 256.f) - mean * mean;
    float rs = 1.0f / sqrtf(var + 1e-5f);
    float4 gg = *(const float4*)(g + lane * 4);
    float4 bb = *(const float4*)(bln + lane * 4);
    unsigned short* o = qt_b + (size_t)row * DN + lane * 4;
    o[0] = f2b((v.x - mean) * rs * gg.x + bb.x);
    o[1] = f2b((v.y - mean) * rs * gg.y + bb.y);
    o[2] = f2b((v.z - mean) * rs * gg.z + bb.z);
    o[3] = f2b((v.w - mean) * rs * gg.w + bb.w);
  }
}

// ================= per-query geo stats -> raw [Q,12] =================
__global__ __launch_bounds__(256) void geo_stats_kernel(
    const float* qpos, const float* spos, const int* offs, const int* s_idx, float* raw) {
  int q = blockIdx.x * 64 + (threadIdx.x >> 2);
  int sub = threadIdx.x & 3;
  int e0 = offs[q], e1 = offs[q + 1];
  float qx = qpos[q * 3 + 0], qy = qpos[q * 3 + 1], qz = qpos[q * 3 + 2];
  float cnt = 0.f, sx = 0.f, sy = 0.f, sz = 0.f, sxx = 0.f, syy = 0.f, szz = 0.f;
  float mnx = 1e30f, mny = 1e30f, mnz = 1e30f, mxx = -1e30f, mxy = -1e30f, mxz = -1e30f;
  for (int e = e0 + sub; e < e1; e += 4) {
    int s = s_idx[e];
    float rx = spos[s * 3 + 0] - qx;
    float ry = spos[s * 3 + 1] - qy;
    float rz = spos[s * 3 + 2] - qz;
    cnt += 1.f;
    sx += rx; sy += ry; sz += rz;
    sxx += rx * rx; syy += ry * ry; szz += rz * rz;
    mnx = fminf(mnx, rx); mny = fminf(mny, ry); mnz = fminf(mnz, rz);
    mxx = fmaxf(mxx, rx); mxy = fmaxf(mxy, ry); mxz = fmaxf(mxz, rz);
  }
#pragma unroll
  for (int msk = 1; msk <= 2; msk <<= 1) {
    cnt += __shfl_xor(cnt, msk);
    sx += __shfl_xor(sx, msk); sy += __shfl_xor(sy, msk); sz += __shfl_xor(sz, msk);
    sxx += __shfl_xor(sxx, msk); syy += __shfl_xor(syy, msk); szz += __shfl_xor(szz, msk);
    mnx = fminf(mnx, __shfl_xor(mnx, msk));
    mny = fminf(mny, __shfl_xor(mny, msk));
    mnz = fminf(mnz, __shfl_xor(mnz, msk));
    mxx = fmaxf(mxx, __shfl_xor(mxx, msk));
    mxy = fmaxf(mxy, __shfl_xor(mxy, msk));
    mxz = fmaxf(mxz, __shfl_xor(mxz, msk));
  }
  if (sub == 0) {
    float c = fmaxf(cnt, 1.f);
    float mx_ = sx / c, my_ = sy / c, mz_ = sz / c;
    float vx = fmaxf(sxx / c - mx_ * mx_, 0.f);
    float vy = fmaxf(syy / c - my_ * my_, 0.f);
    float vz = fmaxf(szz / c - mz_ * mz_, 0.f);
    float* r = raw + (size_t)q * 12;
    r[0] = mx_; r[1] = my_; r[2] = mz_;
    r[3] = sqrtf(vx); r[4] = sqrtf(vy); r[5] = sqrtf(vz);
    r[6] = fminf(fmaxf(mnx, -100.f), 100.f);
    r[7] = fminf(fmaxf(mny, -100.f), 100.f);
    r[8] = fminf(fmaxf(mnz, -100.f), 100.f);
    r[9] = fminf(fmaxf(mxx, -100.f), 100.f);
    r[10] = fminf(fmaxf(mxy, -100.f), 100.f);
    r[11] = fminf(fmaxf(mxz, -100.f), 100.f);
  }
}

// ================= fused geo MLP: one wave per query, shuffle-based layer 2 =================
__global__ __launch_bounds__(256) void geo_mlp_kernel(
    const float* raw, const float* Gw1, const float* Gb1,
    const float* Gw2, const float* Gb2, unsigned short* geo_b) {
  int q = blockIdx.x * 4 + (threadIdx.x >> 6);
  int lane = threadIdx.x & 63;
  float rv[12];
#pragma unroll
  for (int i = 0; i < 12; ++i) rv[i] = raw[(size_t)q * 12 + i];
  int k0 = lane * 2;
  float h[2];
#pragma unroll
  for (int kk = 0; kk < 2; ++kk) {
    float a = Gb1[k0 + kk];
#pragma unroll
    for (int i = 0; i < 12; ++i) a += rv[i] * Gw1[i * GEON + k0 + kk];
    h[kk] = gelu_f(a);
  }
  int j0 = lane * 2;
  float a0 = Gb2[j0], a1 = Gb2[j0 + 1];
#pragma unroll
  for (int k = 0; k < 128; ++k) {
    float hk = __shfl(h[k & 1], k >> 1);
    float2 w = *(const float2*)(Gw2 + (size_t)k * GEON + j0);
    a0 += hk * w.x;
    a1 += hk * w.y;
  }
  ushort2 o;
  o.x = f2b(gelu_f(a0));
  o.y = f2b(gelu_f(a1));
  *(ushort2*)(geo_b + (size_t)q * GEON + j0) = o;
}

// ================= layernorm fp32 [Q,256] -> bf16, one wave per row =================
__global__ __launch_bounds__(256) void ln_kernel(
    const float* x, const float* g, const float* b, unsigned short* out) {
  int row = blockIdx.x * 4 + (threadIdx.x >> 6);
  int lane = threadIdx.x & 63;
  const float* xr = x + (size_t)row * DN;
  float4 v = *(const float4*)(xr + lane * 4);
  float s = v.x + v.y + v.z + v.w;
  float ss = v.x * v.x + v.y * v.y + v.z * v.z + v.w * v.w;
#pragma unroll
  for (int msk = 1; msk <= 32; msk <<= 1) {
    s += __shfl_xor(s, msk);
    ss += __shfl_xor(ss, msk);
  }
  float mean = s * (1.f / 256.f);
  float var = ss * (1.f / 256.f) - mean * mean;
  float rs = 1.0f / sqrtf(var + 1e-5f);
  float4 gg = *(const float4*)(g + lane * 4);
  float4 bb = *(const float4*)(b + lane * 4);
  unsigned short* o = out + (size_t)row * DN + lane * 4;
  o[0] = f2b((v.x - mean) * rs * gg.x + bb.x);
  o[1] = f2b((v.y - mean) * rs * gg.y + bb.y);
  o[2] = f2b((v.z - mean) * rs * gg.z + bb.z);
  o[3] = f2b((v.w - mean) * rs * gg.w + bb.w);
}

// ================= gemm128: m93-class 128x128 tile, BK=32, 4x4 acc/wave =================
// 16 MFMA : 8 ds_read_b128 per wave per K-step (2x better ratio than gemm64).
// A fp32->bf16 conversion fused in staging when A_FP32.
template <bool A_FP32, bool HAS_BIAS, bool DO_GELU, bool HAS_RESID, bool STORE_F32>
__global__ __launch_bounds__(256) void gemm128(
    const void* Ap, const unsigned short* BT, int M, int N, int K,
    const float* bias, const float* resid, float* outF, unsigned short* outB) {
  __shared__ unsigned short As[128][32];   // 8 KB
  __shared__ unsigned short Bs[128][32];   // 8 KB
  int t = threadIdx.x;
  int bm = blockIdx.x * 128, bn = blockIdx.y * 128;
  int w = t >> 6, lane = t & 63;
  int wr = w >> 1, wc = w & 1;             // wave covers rows [wr*64,+64), cols [wc*64,+64)
  int quad = lane >> 4, l16 = lane & 15;
  int srow = t >> 1, shalf = (t & 1) * 16; // staging: thread covers row srow, 16-col half

  f32x4 acc[4][4];
#pragma unroll
  for (int i = 0; i < 4; ++i)
#pragma unroll
    for (int j = 0; j < 4; ++j) acc[i][j] = (f32x4){0.f, 0.f, 0.f, 0.f};

  for (int k0 = 0; k0 < K; k0 += 32) {
    if (A_FP32) {
      const float* Ag = (const float*)Ap + (size_t)(bm + srow) * K + k0 + shalf;
      float4 f0 = *(const float4*)(Ag + 0);
      float4 f1 = *(const float4*)(Ag + 4);
      float4 f2 = *(const float4*)(Ag + 8);
      float4 f3 = *(const float4*)(Ag + 12);
      u16x8 u0, u1;
      u0[0] = f2b(f0.x); u0[1] = f2b(f0.y); u0[2] = f2b(f0.z); u0[3] = f2b(f0.w);
      u0[4] = f2b(f1.x); u0[5] = f2b(f1.y); u0[6] = f2b(f1.z); u0[7] = f2b(f1.w);
      u1[0] = f2b(f2.x); u1[1] = f2b(f2.y); u1[2] = f2b(f2.z); u1[3] = f2b(f2.w);
      u1[4] = f2b(f3.x); u1[5] = f2b(f3.y); u1[6] = f2b(f3.z); u1[7] = f2b(f3.w);
      *reinterpret_cast<u16x8*>(&As[srow][shalf]) = u0;
      *reinterpret_cast<u16x8*>(&As[srow][shalf + 8]) = u1;
    } else {
      const unsigned short* Ag = (const unsigned short*)Ap + (size_t)(bm + srow) * K + k0 + shalf;
      *reinterpret_cast<u16x8*>(&As[srow][shalf]) = *reinterpret_cast<const u16x8*>(Ag);
      *reinterpret_cast<u16x8*>(&As[srow][shalf + 8]) = *reinterpret_cast<const u16x8*>(Ag + 8);
    }
    {
      const unsigned short* Bg = BT + (size_t)(bn + srow) * K + k0 + shalf;
      *reinterpret_cast<u16x8*>(&Bs[srow][shalf]) = *reinterpret_cast<const u16x8*>(Bg);
      *reinterpret_cast<u16x8*>(&Bs[srow][shalf + 8]) = *reinterpret_cast<const u16x8*>(Bg + 8);
    }
    __syncthreads();
    bf16x8 af[4], bf[4];
#pragma unroll
    for (int i = 0; i < 4; ++i)
      af[i] = *reinterpret_cast<const bf16x8*>(&As[wr * 64 + i * 16 + l16][quad * 8]);
#pragma unroll
    for (int j = 0; j < 4; ++j)
      bf[j] = *reinterpret_cast<const bf16x8*>(&Bs[wc * 64 + j * 16 + l16][quad * 8]);
#pragma unroll
    for (int i = 0; i < 4; ++i)
#pragma unroll
      for (int j = 0; j < 4; ++j)
        acc[i][j] = __builtin_amdgcn_mfma_f32_16x16x32_bf16(af[i], bf[j], acc[i][j], 0, 0, 0);
    __syncthreads();
  }

#pragma unroll
  for (int j = 0; j < 4; ++j) {
    int col = bn + wc * 64 + j * 16 + l16;
    float bv = HAS_BIAS ? bias[col] : 0.f;
#pragma unroll
    for (int i = 0; i < 4; ++i) {
#pragma unroll
      for (int r = 0; r < 4; ++r) {
        int row = bm + wr * 64 + i * 16 + quad * 4 + r;
        float v = acc[i][j][r] + bv;
        if (DO_GELU) v = gelu_f(v);
        if (HAS_RESID) v += resid[(size_t)row * N + col];
        if (STORE_F32) outF[(size_t)row * N + col] = v;
        else outB[(size_t)row * N + col] = f2b(v);
      }
    }
  }
}

// ================= generic bf16 MFMA GEMM, 64x64 tile =================
template <bool HAS_BIAS, bool DO_GELU, bool HAS_RESID, bool STORE_F32>
__global__ __launch_bounds__(256) void gemm64(
    const unsigned short* A, const unsigned short* BT, int M, int N, int K,
    const float* bias, const float* resid, float* outF, unsigned short* outB) {
  __shared__ unsigned short As[64][40];
  __shared__ unsigned short Bs[64][40];
  int t = threadIdx.x;
  int bm = blockIdx.x * 64;
  int bn = blockIdx.y * 64;
  int w = t >> 6, lane = t & 63;
  int wr = w >> 1, wc = w & 1;
  int quad = lane >> 4, l16 = lane & 15;
  int row = t >> 2, chunk = t & 3;

  f32x4 acc[2][2];
#pragma unroll
  for (int i = 0; i < 2; ++i)
#pragma unroll
    for (int j = 0; j < 2; ++j) acc[i][j] = (f32x4){0.f, 0.f, 0.f, 0.f};

  for (int k0 = 0; k0 < K; k0 += 32) {
    {
      const unsigned short* Ag = A + (size_t)(bm + row) * K + k0 + chunk * 8;
      *reinterpret_cast<u16x8*>(&As[row][chunk * 8]) = *reinterpret_cast<const u16x8*>(Ag);
    }
    {
      const unsigned short* Bg = BT + (size_t)(bn + row) * K + k0 + chunk * 8;
      *reinterpret_cast<u16x8*>(&Bs[row][chunk * 8]) = *reinterpret_cast<const u16x8*>(Bg);
    }
    __syncthreads();
    bf16x8 a0 = *reinterpret_cast<const bf16x8*>(&As[wr * 32 + l16][quad * 8]);
    bf16x8 a1 = *reinterpret_cast<const bf16x8*>(&As[wr * 32 + 16 + l16][quad * 8]);
    bf16x8 b0 = *reinterpret_cast<const bf16x8*>(&Bs[wc * 32 + l16][quad * 8]);
    bf16x8 b1 = *reinterpret_cast<const bf16x8*>(&Bs[wc * 32 + 16 + l16][quad * 8]);
    acc[0][0] = __builtin_amdgcn_mfma_f32_16x16x32_bf16(a0, b0, acc[0][0], 0, 0, 0);
    acc[0][1] = __builtin_amdgcn_mfma_f32_16x16x32_bf16(a0, b1, acc[0][1], 0, 0, 0);
    acc[1][0] = __builtin_amdgcn_mfma_f32_16x16x32_bf16(a1, b0, acc[1][0], 0, 0, 0);
    acc[1][1] = __builtin_amdgcn_mfma_f32_16x16x32_bf16(a1, b1, acc[1][1], 0, 0, 0);
    __syncthreads();
  }

#pragma unroll
  for (int i = 0; i < 2; ++i)
#pragma unroll
    for (int j = 0; j < 2; ++j) {
      int col = bn + wc * 32 + j * 16 + l16;
      float bv = HAS_BIAS ? bias[col] : 0.f;
#pragma unroll
      for (int r = 0; r < 4; ++r) {
        int rw = bm + wr * 32 + i * 16 + quad * 4 + r;
        float v = acc[i][j][r] + bv;
        if (DO_GELU) v = gelu_f(v);
        if (HAS_RESID) v += resid[(size_t)rw * N + col];
        if (STORE_F32) outF[(size_t)rw * N + col] = v;
        else outB[(size_t)rw * N + col] = f2b(v);
      }
    }
}

// ================= fused Qf|Gf GEMM: blockIdx.y<4 -> Qf (K=256), else Gf (K=128) =================
__global__ __launch_bounds__(256) void qg_gemm(
    const unsigned short* qt_b, const unsigned short* WqT,
    const unsigned short* geo_b, const unsigned short* WgT,
    unsigned short* Qb, unsigned short* Gf_b) {
  __shared__ unsigned short As[64][40];
  __shared__ unsigned short Bs[64][40];
  int t = threadIdx.x;
  int by = blockIdx.y;
  const unsigned short* A; const unsigned short* BT; unsigned short* outB; int K; int bn;
  if (by < 4) { A = qt_b;  BT = WqT; outB = Qb;   K = 256; bn = by * 64; }
  else        { A = geo_b; BT = WgT; outB = Gf_b; K = 128; bn = (by - 4) * 64; }
  int bm = blockIdx.x * 64;
  int w = t >> 6, lane = t & 63;
  int wr = w >> 1, wc = w & 1;
  int quad = lane >> 4, l16 = lane & 15;
  int row = t >> 2, chunk = t & 3;

  f32x4 acc[2][2];
#pragma unroll
  for (int i = 0; i < 2; ++i)
#pragma unroll
    for (int j = 0; j < 2; ++j) acc[i][j] = (f32x4){0.f, 0.f, 0.f, 0.f};

  for (int k0 = 0; k0 < K; k0 += 32) {
    *reinterpret_cast<u16x8*>(&As[row][chunk * 8]) =
        *reinterpret_cast<const u16x8*>(A + (size_t)(bm + row) * K + k0 + chunk * 8);
    *reinterpret_cast<u16x8*>(&Bs[row][chunk * 8]) =
        *reinterpret_cast<const u16x8*>(BT + (size_t)(bn + row) * K + k0 + chunk * 8);
    __syncthreads();
    bf16x8 a0 = *reinterpret_cast<const bf16x8*>(&As[wr * 32 + l16][quad * 8]);
    bf16x8 a1 = *reinterpret_cast<const bf16x8*>(&As[wr * 32 + 16 + l16][quad * 8]);
    bf16x8 b0 = *reinterpret_cast<const bf16x8*>(&Bs[wc * 32 + l16][quad * 8]);
    bf16x8 b1 = *reinterpret_cast<const bf16x8*>(&Bs[wc * 32 + 16 + l16][quad * 8]);
    acc[0][0] = __builtin_amdgcn_mfma_f32_16x16x32_bf16(a0, b0, acc[0][0], 0, 0, 0);
    acc[0][1] = __builtin_amdgcn_mfma_f32_16x16x32_bf16(a0, b1, acc[0][1], 0, 0, 0);
    acc[1][0] = __builtin_amdgcn_mfma_f32_16x16x32_bf16(a1, b0, acc[1][0], 0, 0, 0);
    acc[1][1] = __builtin_amdgcn_mfma_f32_16x16x32_bf16(a1, b1, acc[1][1], 0, 0, 0);
    __syncthreads();
  }
#pragma unroll
  for (int i = 0; i < 2; ++i)
#pragma unroll
    for (int j = 0; j < 2; ++j) {
      int col = bn + wc * 32 + j * 16 + l16;
#pragma unroll
      for (int r = 0; r < 4; ++r) {
        int rw = bm + wr * 32 + i * 16 + quad * 4 + r;
        outB[(size_t)rw * DN + col] = f2b(acc[i][j][r]);
      }
    }
}

// ================= edge attention (one wave/query, 2 edges/iter) =================
__global__ __launch_bounds__(256) void attn_edge_kernel(
    const unsigned short* Qb, const unsigned short* Gfb, const unsigned short* KVb,
    const int* s_idx, const int* offs, const float* log_tau, unsigned short* attn_b) {
  int q = blockIdx.x * 4 + (threadIdx.x >> 6);
  int lane = threadIdx.x & 63;
  int half = lane >> 5;
  int sl = lane & 31;
  int d0 = sl * 8;
  int e0 = offs[q], e1 = offs[q + 1];
  float invs = expf(-log_tau[0]) * 0.17677669529663687f;  // 1/(sqrt(32)*tau)
  u16x8 qu = *(const u16x8*)(Qb + (size_t)q * DN + d0);
  u16x8 gu = *(const u16x8*)(Gfb + (size_t)q * DN + d0);
  float qf[8], gf[8];
#pragma unroll
  for (int j = 0; j < 8; ++j) { qf[j] = b2f(qu[j]) * invs; gf[j] = b2f(gu[j]); }
  const float NEG = -1e30f;
  float m = -INFINITY, l = 0.f;
  float a[8];
#pragma unroll
  for (int j = 0; j < 8; ++j) a[j] = 0.f;
  for (int e = e0; e < e1; e += 2) {
    int ee = e + half;
    bool valid = ee < e1;
    int s = s_idx[valid ? ee : (e1 - 1)];
    const unsigned short* kr = KVb + (size_t)s * 512 + d0;
    u16x8 ku = *(const u16x8*)kr;
    u16x8 vu = *(const u16x8*)(kr + 256);
    float p = 0.f;
#pragma unroll
    for (int j = 0; j < 8; ++j) p += qf[j] * b2f(ku[j]);
    p += __shfl_xor(p, 1);
    p += __shfl_xor(p, 2);
    if (!valid) p = -INFINITY;
    float mnew = fmaxf(m, p);
    float sc = (m > NEG) ? __expf(m - mnew) : 0.f;
    float we = valid ? __expf(p - mnew) : 0.f;
    l = l * sc + we;
#pragma unroll
    for (int j = 0; j < 8; ++j) a[j] = a[j] * sc + we * (b2f(vu[j]) + gf[j]);
    m = mnew;
  }
  float om = __shfl_xor(m, 32);
  float ol = __shfl_xor(l, 32);
  float M2 = fmaxf(m, om);
  float wsc = (m > NEG) ? __expf(m - M2) : 0.f;
  float wo = (om > NEG) ? __expf(om - M2) : 0.f;
  l = l * wsc + ol * wo;
#pragma unroll
  for (int j = 0; j < 8; ++j) {
    float oa = __shfl_xor(a[j], 32);
    a[j] = a[j] * wsc + oa * wo;
  }
  float M = fmaxf(M2, 0.f);
  float em = (M2 > NEG) ? __expf(M2 - M) : 0.f;
  float denom = fmaxf(l * em, 1e-8f);
  float f = em / denom;
  if (half == 0) {
    u16x8 o;
#pragma unroll
    for (int j = 0; j < 8; ++j) o[j] = f2b(a[j] * f);
    *(u16x8*)(attn_b + (size_t)q * DN + d0) = o;
  }
}

extern "C" void kernel_launch(void* const* d_in, const int* in_sizes, int n_in,
                              void* d_out, int out_size, void* d_ws, size_t ws_size,
                              hipStream_t stream) {
  const float* query_tokens  = (const float*)d_in[0];
  const float* query_pos     = (const float*)d_in[1];
  const float* support_feats = (const float*)d_in[2];
  const float* support_pos   = (const float*)d_in[3];
  const float* Wq  = (const float*)d_in[4];
  const float* Wk  = (const float*)d_in[5];
  const float* Wv  = (const float*)d_in[6];
  const float* Wg  = (const float*)d_in[7];
  const float* Wo  = (const float*)d_in[8];
  const float* bo  = (const float*)d_in[9];
  const float* log_tau = (const float*)d_in[10];
  const float* ln1_g = (const float*)d_in[11];
  const float* ln1_b = (const float*)d_in[12];
  const float* ln2_g = (const float*)d_in[13];
  const float* ln2_b = (const float*)d_in[14];
  const float* Wf1 = (const float*)d_in[15];
  const float* bf1 = (const float*)d_in[16];
  const float* Wf2 = (const float*)d_in[17];
  const float* bf2 = (const float*)d_in[18];
  const float* Gw1 = (const float*)d_in[19];
  const float* Gb1 = (const float*)d_in[20];
  const float* Gw2 = (const float*)d_in[21];
  const float* Gb2 = (const float*)d_in[22];
  const int* q_idx = (const int*)d_in[23];
  const int* s_idx = (const int*)d_in[24];
  float* out = (float*)d_out;

  char* ws = (char*)d_ws;
  size_t off = 0;
  auto alloc = [&](size_t bytes) -> void* {
    void* p = ws + off;
    off = (off + bytes + 255) & ~(size_t)255;
    return p;
  };
  unsigned short* WqT  = (unsigned short*)alloc(65536 * 2);
  unsigned short* WkvT = (unsigned short*)alloc(131072 * 2);
  unsigned short* WgT  = (unsigned short*)alloc(32768 * 2);
  unsigned short* WoT  = (unsigned short*)alloc(65536 * 2);
  unsigned short* Wf1T = (unsigned short*)alloc(131072 * 2);
  unsigned short* Wf2T = (unsigned short*)alloc(131072 * 2);
  int* offs            = (int*)alloc((QN + 1) * 4);
  float* raw           = (float*)alloc((size_t)QN * 12 * 4);
  unsigned short* geo_b = (unsigned short*)alloc((size_t)QN * GEON * 2);
  unsigned short* qt_b  = (unsigned short*)alloc((size_t)QN * DN * 2);
  unsigned short* Qb    = (unsigned short*)alloc((size_t)QN * DN * 2);
  unsigned short* Gf_b  = (unsigned short*)alloc((size_t)QN * DN * 2);
  unsigned short* KVb   = (unsigned short*)alloc((size_t)SN * 512 * 2);
  unsigned short* attn_b = (unsigned short*)alloc((size_t)QN * DN * 2);
  float* x1             = (float*)alloc((size_t)QN * DN * 4);
  unsigned short* z_b   = (unsigned short*)alloc((size_t)QN * DN * 2);
  unsigned short* h_b   = (unsigned short*)alloc((size_t)QN * FFNN * 2);

  // 1. prep: weight transpose | segment offsets | LN1
  prep_kernel<<<TRB + SOB + QN / 4, 256, 0, stream>>>(
      Wq, Wk, Wv, Wg, Wo, Wf1, Wf2, WqT, WkvT, WgT, WoT, Wf1T, Wf2T,
      q_idx, offs, query_tokens, ln1_g, ln1_b, qt_b);
  // 2. geo stats
  geo_stats_kernel<<<QN / 64, 256, 0, stream>>>(query_pos, support_pos, offs, s_idx, raw);
  // 3. geo MLP (fused, shuffle-based)
  geo_mlp_kernel<<<QN / 4, 256, 0, stream>>>(raw, Gw1, Gb1, Gw2, Gb2, geo_b);
  // 4. KV = support_feats @ [Wk|Wv] — gemm128, fp32 A converted in staging
  gemm128<true, false, false, false, false><<<dim3(SN / 128, 512 / 128), 256, 0, stream>>>(
      support_feats, WkvT, SN, 512, 256, nullptr, nullptr, nullptr, KVb);
  // 5. Qf | Gf fused
  qg_gemm<<<dim3(QN / 64, 8), 256, 0, stream>>>(qt_b, WqT, geo_b, WgT, Qb, Gf_b);
  // 6. edge attention
  attn_edge_kernel<<<QN / 4, 256, 0, stream>>>(Qb, Gf_b, KVb, s_idx, offs, log_tau, attn_b);
  // 7. x1 = attn @ Wo + bo + query_tokens (512-block gemm64, proven)
  gemm64<true, false, true, true><<<dim3(QN / 64, DN / 64), 256, 0, stream>>>(
      attn_b, WoT, QN, DN, 256, bo, query_tokens, x1, nullptr);
  // 8. LN2
  ln_kernel<<<QN / 4, 256, 0, stream>>>(x1, ln2_g, ln2_b, z_b);
  // 9. h = gelu(z @ Wf1 + bf1) — gemm128
  gemm128<false, true, true, false, false><<<dim3(QN / 128, FFNN / 128), 256, 0, stream>>>(
      z_b, Wf1T, QN, FFNN, 256, bf1, nullptr, nullptr, h_b);
  // 10. out = h @ Wf2 + bf2 + x1
  gemm64<true, false, true, true><<<dim3(QN / 64, DN / 64), 256, 0, stream>>>(
      h_b, Wf2T, QN, DN, 512, bf2, x1, out, nullptr);

  (void)in_sizes; (void)n_in; (void)out_size; (void)ws_size;
}

// Round 11
// 263.449 us; speedup vs baseline: 1.0359x; 1.0359x over previous
//
#include <hip/hip_runtime.h>
#include <math.h>

#define QN 8192
#define SN 32768
#define EN 131072
#define DN 256
#define HN 8
#define HDN 32
#define GEON 128
#define FFNN 512

typedef __attribute__((ext_vector_type(8))) short bf16x8;
typedef __attribute__((ext_vector_type(8))) unsigned short u16x8;
typedef __attribute__((ext_vector_type(4))) unsigned short u16x4;
typedef __attribute__((ext_vector_type(4))) float f32x4;

__device__ __forceinline__ unsigned short f2b(float f) {
  union { float f; unsigned u; } v; v.f = f;
  unsigned u = v.u;
  u += 0x7fffu + ((u >> 16) & 1u);   // round-to-nearest-even
  return (unsigned short)(u >> 16);
}
__device__ __forceinline__ float b2f(unsigned short h) {
  union { unsigned u; float f; } v; v.u = ((unsigned)h) << 16; return v.f;
}
__device__ __forceinline__ float gelu_f(float x) {
  return 0.5f * x * (1.0f + erff(x * 0.70710678118654752440f));
}

// ================= prep kernel: transpose(136) | seg_offsets(33) | LN1(2048) =================
#define TRB 136
#define SOB 33
__global__ __launch_bounds__(256) void prep_kernel(
    const float* Wq, const float* Wk, const float* Wv, const float* Wg,
    const float* Wo, const float* Wf1, const float* Wf2,
    unsigned short* WqT, unsigned short* WkvT, unsigned short* WgT,
    unsigned short* WoT, unsigned short* Wf1T, unsigned short* Wf2T,
    const int* q_idx, int* offs,
    const float* x, const float* g, const float* bln, unsigned short* qt_b) {
  __shared__ float ts[64][65];
  int b = blockIdx.x;
  int t = threadIdx.x;
  if (b < TRB) {
    const float* src; unsigned short* dst; int K, N, tile;
    if (b < 16)       { src = Wq;  dst = WqT;          K = 256; N = 256; tile = b; }
    else if (b < 32)  { src = Wk;  dst = WkvT;         K = 256; N = 256; tile = b - 16; }
    else if (b < 48)  { src = Wv;  dst = WkvT + 65536; K = 256; N = 256; tile = b - 32; }
    else if (b < 56)  { src = Wg;  dst = WgT;          K = 128; N = 256; tile = b - 48; }
    else if (b < 72)  { src = Wo;  dst = WoT;          K = 256; N = 256; tile = b - 56; }
    else if (b < 104) { src = Wf1; dst = Wf1T;         K = 256; N = 512; tile = b - 72; }
    else              { src = Wf2; dst = Wf2T;         K = 512; N = 256; tile = b - 104; }
    int ktiles = K >> 6;
    int k0 = (tile % ktiles) * 64, n0 = (tile / ktiles) * 64;
    int c4 = (t & 15) * 4;
    int r = t >> 4;
#pragma unroll
    for (int p = 0; p < 4; ++p) {
      int row = p * 16 + r;
      float4 v = *(const float4*)(src + (size_t)(k0 + row) * N + n0 + c4);
      ts[row][c4 + 0] = v.x; ts[row][c4 + 1] = v.y;
      ts[row][c4 + 2] = v.z; ts[row][c4 + 3] = v.w;
    }
    __syncthreads();
#pragma unroll
    for (int p = 0; p < 4; ++p) {
      int n = p * 16 + r;
      ushort4 o;
      o.x = f2b(ts[c4 + 0][n]); o.y = f2b(ts[c4 + 1][n]);
      o.z = f2b(ts[c4 + 2][n]); o.w = f2b(ts[c4 + 3][n]);
      *(ushort4*)(dst + (size_t)(n0 + n) * K + k0 + c4) = o;
    }
  } else if (b < TRB + SOB) {
    int i = (b - TRB) * 256 + t;
    if (i > QN) return;
    int lo = 0, hi = EN;
    while (lo < hi) {
      int mid = (lo + hi) >> 1;
      if (q_idx[mid] < i) lo = mid + 1; else hi = mid;
    }
    offs[i] = lo;
  } else {
    int row = (b - TRB - SOB) * 4 + (t >> 6);
    int lane = t & 63;
    const float* xr = x + (size_t)row * DN;
    float4 v = *(const float4*)(xr + lane * 4);
    float s = v.x + v.y + v.z + v.w;
    float ss = v.x * v.x + v.y * v.y + v.z * v.z + v.w * v.w;
#pragma unroll
    for (int msk = 1; msk <= 32; msk <<= 1) {
      s += __shfl_xor(s, msk);
      ss += __shfl_xor(ss, msk);
    }
    float mean = s * (1.f / 256.f);
    float var = ss * (1.f / 256.f) - mean * mean;
    float rs = 1.0f / sqrtf(var + 1e-5f);
    float4 gg = *(const float4*)(g + lane * 4);
    float4 bb = *(const float4*)(bln + lane * 4);
    unsigned short* o = qt_b + (size_t)row * DN + lane * 4;
    o[0] = f2b((v.x - mean) * rs * gg.x + bb.x);
    o[1] = f2b((v.y - mean) * rs * gg.y + bb.y);
    o[2] = f2b((v.z - mean) * rs * gg.z + bb.z);
    o[3] = f2b((v.w - mean) * rs * gg.w + bb.w);
  }
}

// ================= per-query geo stats -> raw [Q,12] =================
__global__ __launch_bounds__(256) void geo_stats_kernel(
    const float* qpos, const float* spos, const int* offs, const int* s_idx, float* raw) {
  int q = blockIdx.x * 64 + (threadIdx.x >> 2);
  int sub = threadIdx.x & 3;
  int e0 = offs[q], e1 = offs[q + 1];
  float qx = qpos[q * 3 + 0], qy = qpos[q * 3 + 1], qz = qpos[q * 3 + 2];
  float cnt = 0.f, sx = 0.f, sy = 0.f, sz = 0.f, sxx = 0.f, syy = 0.f, szz = 0.f;
  float mnx = 1e30f, mny = 1e30f, mnz = 1e30f, mxx = -1e30f, mxy = -1e30f, mxz = -1e30f;
  for (int e = e0 + sub; e < e1; e += 4) {
    int s = s_idx[e];
    float rx = spos[s * 3 + 0] - qx;
    float ry = spos[s * 3 + 1] - qy;
    float rz = spos[s * 3 + 2] - qz;
    cnt += 1.f;
    sx += rx; sy += ry; sz += rz;
    sxx += rx * rx; syy += ry * ry; szz += rz * rz;
    mnx = fminf(mnx, rx); mny = fminf(mny, ry); mnz = fminf(mnz, rz);
    mxx = fmaxf(mxx, rx); mxy = fmaxf(mxy, ry); mxz = fmaxf(mxz, rz);
  }
#pragma unroll
  for (int msk = 1; msk <= 2; msk <<= 1) {
    cnt += __shfl_xor(cnt, msk);
    sx += __shfl_xor(sx, msk); sy += __shfl_xor(sy, msk); sz += __shfl_xor(sz, msk);
    sxx += __shfl_xor(sxx, msk); syy += __shfl_xor(syy, msk); szz += __shfl_xor(szz, msk);
    mnx = fminf(mnx, __shfl_xor(mnx, msk));
    mny = fminf(mny, __shfl_xor(mny, msk));
    mnz = fminf(mnz, __shfl_xor(mnz, msk));
    mxx = fmaxf(mxx, __shfl_xor(mxx, msk));
    mxy = fmaxf(mxy, __shfl_xor(mxy, msk));
    mxz = fmaxf(mxz, __shfl_xor(mxz, msk));
  }
  if (sub == 0) {
    float c = fmaxf(cnt, 1.f);
    float mx_ = sx / c, my_ = sy / c, mz_ = sz / c;
    float vx = fmaxf(sxx / c - mx_ * mx_, 0.f);
    float vy = fmaxf(syy / c - my_ * my_, 0.f);
    float vz = fmaxf(szz / c - mz_ * mz_, 0.f);
    float* r = raw + (size_t)q * 12;
    r[0] = mx_; r[1] = my_; r[2] = mz_;
    r[3] = sqrtf(vx); r[4] = sqrtf(vy); r[5] = sqrtf(vz);
    r[6] = fminf(fmaxf(mnx, -100.f), 100.f);
    r[7] = fminf(fmaxf(mny, -100.f), 100.f);
    r[8] = fminf(fmaxf(mnz, -100.f), 100.f);
    r[9] = fminf(fmaxf(mxx, -100.f), 100.f);
    r[10] = fminf(fmaxf(mxy, -100.f), 100.f);
    r[11] = fminf(fmaxf(mxz, -100.f), 100.f);
  }
}

// ================= fused geo MLP: one wave per query, shuffle-based layer 2 =================
__global__ __launch_bounds__(256) void geo_mlp_kernel(
    const float* raw, const float* Gw1, const float* Gb1,
    const float* Gw2, const float* Gb2, unsigned short* geo_b) {
  int q = blockIdx.x * 4 + (threadIdx.x >> 6);
  int lane = threadIdx.x & 63;
  float rv[12];
#pragma unroll
  for (int i = 0; i < 12; ++i) rv[i] = raw[(size_t)q * 12 + i];
  int k0 = lane * 2;
  float h[2];
#pragma unroll
  for (int kk = 0; kk < 2; ++kk) {
    float a = Gb1[k0 + kk];
#pragma unroll
    for (int i = 0; i < 12; ++i) a += rv[i] * Gw1[i * GEON + k0 + kk];
    h[kk] = gelu_f(a);
  }
  int j0 = lane * 2;
  float a0 = Gb2[j0], a1 = Gb2[j0 + 1];
#pragma unroll
  for (int k = 0; k < 128; ++k) {
    float hk = __shfl(h[k & 1], k >> 1);
    float2 w = *(const float2*)(Gw2 + (size_t)k * GEON + j0);
    a0 += hk * w.x;
    a1 += hk * w.y;
  }
  ushort2 o;
  o.x = f2b(gelu_f(a0));
  o.y = f2b(gelu_f(a1));
  *(ushort2*)(geo_b + (size_t)q * GEON + j0) = o;
}

// ================= layernorm fp32 [Q,256] -> bf16, one wave per row =================
__global__ __launch_bounds__(256) void ln_kernel(
    const float* x, const float* g, const float* b, unsigned short* out) {
  int row = blockIdx.x * 4 + (threadIdx.x >> 6);
  int lane = threadIdx.x & 63;
  const float* xr = x + (size_t)row * DN;
  float4 v = *(const float4*)(xr + lane * 4);
  float s = v.x + v.y + v.z + v.w;
  float ss = v.x * v.x + v.y * v.y + v.z * v.z + v.w * v.w;
#pragma unroll
  for (int msk = 1; msk <= 32; msk <<= 1) {
    s += __shfl_xor(s, msk);
    ss += __shfl_xor(ss, msk);
  }
  float mean = s * (1.f / 256.f);
  float var = ss * (1.f / 256.f) - mean * mean;
  float rs = 1.0f / sqrtf(var + 1e-5f);
  float4 gg = *(const float4*)(g + lane * 4);
  float4 bb = *(const float4*)(b + lane * 4);
  unsigned short* o = out + (size_t)row * DN + lane * 4;
  o[0] = f2b((v.x - mean) * rs * gg.x + bb.x);
  o[1] = f2b((v.y - mean) * rs * gg.y + bb.y);
  o[2] = f2b((v.z - mean) * rs * gg.z + bb.z);
  o[3] = f2b((v.w - mean) * rs * gg.w + bb.w);
}

// ================= gemm128: 128x128 tile, BK=32, 4x4 acc/wave, pad-40 LDS =================
// Pad 40 (80 B row stride): fragment reads 2-way bank-aliased (free, m136),
// staging writes 4-way (1.58x). 20 KB LDS -> 3 blocks/CU possible.
template <bool A_FP32, bool HAS_BIAS, bool DO_GELU, bool HAS_RESID, bool STORE_F32>
__global__ __launch_bounds__(256) void gemm128(
    const void* Ap, const unsigned short* BT, int M, int N, int K,
    const float* bias, const float* resid, float* outF, unsigned short* outB) {
  __shared__ unsigned short As[128][40];   // 10 KB
  __shared__ unsigned short Bs[128][40];   // 10 KB
  int t = threadIdx.x;
  int bm = blockIdx.x * 128, bn = blockIdx.y * 128;
  int w = t >> 6, lane = t & 63;
  int wr = w >> 1, wc = w & 1;
  int quad = lane >> 4, l16 = lane & 15;
  int srow = t >> 1, shalf = (t & 1) * 16;

  f32x4 acc[4][4];
#pragma unroll
  for (int i = 0; i < 4; ++i)
#pragma unroll
    for (int j = 0; j < 4; ++j) acc[i][j] = (f32x4){0.f, 0.f, 0.f, 0.f};

  for (int k0 = 0; k0 < K; k0 += 32) {
    if (A_FP32) {
      const float* Ag = (const float*)Ap + (size_t)(bm + srow) * K + k0 + shalf;
      float4 f0 = *(const float4*)(Ag + 0);
      float4 f1 = *(const float4*)(Ag + 4);
      float4 f2 = *(const float4*)(Ag + 8);
      float4 f3 = *(const float4*)(Ag + 12);
      u16x8 u0, u1;
      u0[0] = f2b(f0.x); u0[1] = f2b(f0.y); u0[2] = f2b(f0.z); u0[3] = f2b(f0.w);
      u0[4] = f2b(f1.x); u0[5] = f2b(f1.y); u0[6] = f2b(f1.z); u0[7] = f2b(f1.w);
      u1[0] = f2b(f2.x); u1[1] = f2b(f2.y); u1[2] = f2b(f2.z); u1[3] = f2b(f2.w);
      u1[4] = f2b(f3.x); u1[5] = f2b(f3.y); u1[6] = f2b(f3.z); u1[7] = f2b(f3.w);
      *reinterpret_cast<u16x8*>(&As[srow][shalf]) = u0;
      *reinterpret_cast<u16x8*>(&As[srow][shalf + 8]) = u1;
    } else {
      const unsigned short* Ag = (const unsigned short*)Ap + (size_t)(bm + srow) * K + k0 + shalf;
      *reinterpret_cast<u16x8*>(&As[srow][shalf]) = *reinterpret_cast<const u16x8*>(Ag);
      *reinterpret_cast<u16x8*>(&As[srow][shalf + 8]) = *reinterpret_cast<const u16x8*>(Ag + 8);
    }
    {
      const unsigned short* Bg = BT + (size_t)(bn + srow) * K + k0 + shalf;
      *reinterpret_cast<u16x8*>(&Bs[srow][shalf]) = *reinterpret_cast<const u16x8*>(Bg);
      *reinterpret_cast<u16x8*>(&Bs[srow][shalf + 8]) = *reinterpret_cast<const u16x8*>(Bg + 8);
    }
    __syncthreads();
    bf16x8 af[4], bf[4];
#pragma unroll
    for (int i = 0; i < 4; ++i)
      af[i] = *reinterpret_cast<const bf16x8*>(&As[wr * 64 + i * 16 + l16][quad * 8]);
#pragma unroll
    for (int j = 0; j < 4; ++j)
      bf[j] = *reinterpret_cast<const bf16x8*>(&Bs[wc * 64 + j * 16 + l16][quad * 8]);
#pragma unroll
    for (int i = 0; i < 4; ++i)
#pragma unroll
      for (int j = 0; j < 4; ++j)
        acc[i][j] = __builtin_amdgcn_mfma_f32_16x16x32_bf16(af[i], bf[j], acc[i][j], 0, 0, 0);
    __syncthreads();
  }

#pragma unroll
  for (int j = 0; j < 4; ++j) {
    int col = bn + wc * 64 + j * 16 + l16;
    float bv = HAS_BIAS ? bias[col] : 0.f;
#pragma unroll
    for (int i = 0; i < 4; ++i) {
#pragma unroll
      for (int r = 0; r < 4; ++r) {
        int row = bm + wr * 64 + i * 16 + quad * 4 + r;
        float v = acc[i][j][r] + bv;
        if (DO_GELU) v = gelu_f(v);
        if (HAS_RESID) v += resid[(size_t)row * N + col];
        if (STORE_F32) outF[(size_t)row * N + col] = v;
        else outB[(size_t)row * N + col] = f2b(v);
      }
    }
  }
}

// ================= generic bf16 MFMA GEMM, 64x64 tile =================
template <bool HAS_BIAS, bool DO_GELU, bool HAS_RESID, bool STORE_F32>
__global__ __launch_bounds__(256) void gemm64(
    const unsigned short* A, const unsigned short* BT, int M, int N, int K,
    const float* bias, const float* resid, float* outF, unsigned short* outB) {
  __shared__ unsigned short As[64][40];
  __shared__ unsigned short Bs[64][40];
  int t = threadIdx.x;
  int bm = blockIdx.x * 64;
  int bn = blockIdx.y * 64;
  int w = t >> 6, lane = t & 63;
  int wr = w >> 1, wc = w & 1;
  int quad = lane >> 4, l16 = lane & 15;
  int row = t >> 2, chunk = t & 3;

  f32x4 acc[2][2];
#pragma unroll
  for (int i = 0; i < 2; ++i)
#pragma unroll
    for (int j = 0; j < 2; ++j) acc[i][j] = (f32x4){0.f, 0.f, 0.f, 0.f};

  for (int k0 = 0; k0 < K; k0 += 32) {
    {
      const unsigned short* Ag = A + (size_t)(bm + row) * K + k0 + chunk * 8;
      *reinterpret_cast<u16x8*>(&As[row][chunk * 8]) = *reinterpret_cast<const u16x8*>(Ag);
    }
    {
      const unsigned short* Bg = BT + (size_t)(bn + row) * K + k0 + chunk * 8;
      *reinterpret_cast<u16x8*>(&Bs[row][chunk * 8]) = *reinterpret_cast<const u16x8*>(Bg);
    }
    __syncthreads();
    bf16x8 a0 = *reinterpret_cast<const bf16x8*>(&As[wr * 32 + l16][quad * 8]);
    bf16x8 a1 = *reinterpret_cast<const bf16x8*>(&As[wr * 32 + 16 + l16][quad * 8]);
    bf16x8 b0 = *reinterpret_cast<const bf16x8*>(&Bs[wc * 32 + l16][quad * 8]);
    bf16x8 b1 = *reinterpret_cast<const bf16x8*>(&Bs[wc * 32 + 16 + l16][quad * 8]);
    acc[0][0] = __builtin_amdgcn_mfma_f32_16x16x32_bf16(a0, b0, acc[0][0], 0, 0, 0);
    acc[0][1] = __builtin_amdgcn_mfma_f32_16x16x32_bf16(a0, b1, acc[0][1], 0, 0, 0);
    acc[1][0] = __builtin_amdgcn_mfma_f32_16x16x32_bf16(a1, b0, acc[1][0], 0, 0, 0);
    acc[1][1] = __builtin_amdgcn_mfma_f32_16x16x32_bf16(a1, b1, acc[1][1], 0, 0, 0);
    __syncthreads();
  }

#pragma unroll
  for (int i = 0; i < 2; ++i)
#pragma unroll
    for (int j = 0; j < 2; ++j) {
      int col = bn + wc * 32 + j * 16 + l16;
      float bv = HAS_BIAS ? bias[col] : 0.f;
#pragma unroll
      for (int r = 0; r < 4; ++r) {
        int rw = bm + wr * 32 + i * 16 + quad * 4 + r;
        float v = acc[i][j][r] + bv;
        if (DO_GELU) v = gelu_f(v);
        if (HAS_RESID) v += resid[(size_t)rw * N + col];
        if (STORE_F32) outF[(size_t)rw * N + col] = v;
        else outB[(size_t)rw * N + col] = f2b(v);
      }
    }
}

// ================= fused Qf|Gf GEMM: blockIdx.y<4 -> Qf (K=256), else Gf (K=128) =================
__global__ __launch_bounds__(256) void qg_gemm(
    const unsigned short* qt_b, const unsigned short* WqT,
    const unsigned short* geo_b, const unsigned short* WgT,
    unsigned short* Qb, unsigned short* Gf_b) {
  __shared__ unsigned short As[64][40];
  __shared__ unsigned short Bs[64][40];
  int t = threadIdx.x;
  int by = blockIdx.y;
  const unsigned short* A; const unsigned short* BT; unsigned short* outB; int K; int bn;
  if (by < 4) { A = qt_b;  BT = WqT; outB = Qb;   K = 256; bn = by * 64; }
  else        { A = geo_b; BT = WgT; outB = Gf_b; K = 128; bn = (by - 4) * 64; }
  int bm = blockIdx.x * 64;
  int w = t >> 6, lane = t & 63;
  int wr = w >> 1, wc = w & 1;
  int quad = lane >> 4, l16 = lane & 15;
  int row = t >> 2, chunk = t & 3;

  f32x4 acc[2][2];
#pragma unroll
  for (int i = 0; i < 2; ++i)
#pragma unroll
    for (int j = 0; j < 2; ++j) acc[i][j] = (f32x4){0.f, 0.f, 0.f, 0.f};

  for (int k0 = 0; k0 < K; k0 += 32) {
    *reinterpret_cast<u16x8*>(&As[row][chunk * 8]) =
        *reinterpret_cast<const u16x8*>(A + (size_t)(bm + row) * K + k0 + chunk * 8);
    *reinterpret_cast<u16x8*>(&Bs[row][chunk * 8]) =
        *reinterpret_cast<const u16x8*>(BT + (size_t)(bn + row) * K + k0 + chunk * 8);
    __syncthreads();
    bf16x8 a0 = *reinterpret_cast<const bf16x8*>(&As[wr * 32 + l16][quad * 8]);
    bf16x8 a1 = *reinterpret_cast<const bf16x8*>(&As[wr * 32 + 16 + l16][quad * 8]);
    bf16x8 b0 = *reinterpret_cast<const bf16x8*>(&Bs[wc * 32 + l16][quad * 8]);
    bf16x8 b1 = *reinterpret_cast<const bf16x8*>(&Bs[wc * 32 + 16 + l16][quad * 8]);
    acc[0][0] = __builtin_amdgcn_mfma_f32_16x16x32_bf16(a0, b0, acc[0][0], 0, 0, 0);
    acc[0][1] = __builtin_amdgcn_mfma_f32_16x16x32_bf16(a0, b1, acc[0][1], 0, 0, 0);
    acc[1][0] = __builtin_amdgcn_mfma_f32_16x16x32_bf16(a1, b0, acc[1][0], 0, 0, 0);
    acc[1][1] = __builtin_amdgcn_mfma_f32_16x16x32_bf16(a1, b1, acc[1][1], 0, 0, 0);
    __syncthreads();
  }
#pragma unroll
  for (int i = 0; i < 2; ++i)
#pragma unroll
    for (int j = 0; j < 2; ++j) {
      int col = bn + wc * 32 + j * 16 + l16;
#pragma unroll
      for (int r = 0; r < 4; ++r) {
        int rw = bm + wr * 32 + i * 16 + quad * 4 + r;
        outB[(size_t)rw * DN + col] = f2b(acc[i][j][r]);
      }
    }
}

// ================= edge attention (one wave/query, 2 edges/iter) =================
__global__ __launch_bounds__(256) void attn_edge_kernel(
    const unsigned short* Qb, const unsigned short* Gfb, const unsigned short* KVb,
    const int* s_idx, const int* offs, const float* log_tau, unsigned short* attn_b) {
  int q = blockIdx.x * 4 + (threadIdx.x >> 6);
  int lane = threadIdx.x & 63;
  int half = lane >> 5;
  int sl = lane & 31;
  int d0 = sl * 8;
  int e0 = offs[q], e1 = offs[q + 1];
  float invs = expf(-log_tau[0]) * 0.17677669529663687f;  // 1/(sqrt(32)*tau)
  u16x8 qu = *(const u16x8*)(Qb + (size_t)q * DN + d0);
  u16x8 gu = *(const u16x8*)(Gfb + (size_t)q * DN + d0);
  float qf[8], gf[8];
#pragma unroll
  for (int j = 0; j < 8; ++j) { qf[j] = b2f(qu[j]) * invs; gf[j] = b2f(gu[j]); }
  const float NEG = -1e30f;
  float m = -INFINITY, l = 0.f;
  float a[8];
#pragma unroll
  for (int j = 0; j < 8; ++j) a[j] = 0.f;
  for (int e = e0; e < e1; e += 2) {
    int ee = e + half;
    bool valid = ee < e1;
    int s = s_idx[valid ? ee : (e1 - 1)];
    const unsigned short* kr = KVb + (size_t)s * 512 + d0;
    u16x8 ku = *(const u16x8*)kr;
    u16x8 vu = *(const u16x8*)(kr + 256);
    float p = 0.f;
#pragma unroll
    for (int j = 0; j < 8; ++j) p += qf[j] * b2f(ku[j]);
    p += __shfl_xor(p, 1);
    p += __shfl_xor(p, 2);
    if (!valid) p = -INFINITY;
    float mnew = fmaxf(m, p);
    float sc = (m > NEG) ? __expf(m - mnew) : 0.f;
    float we = valid ? __expf(p - mnew) : 0.f;
    l = l * sc + we;
#pragma unroll
    for (int j = 0; j < 8; ++j) a[j] = a[j] * sc + we * (b2f(vu[j]) + gf[j]);
    m = mnew;
  }
  float om = __shfl_xor(m, 32);
  float ol = __shfl_xor(l, 32);
  float M2 = fmaxf(m, om);
  float wsc = (m > NEG) ? __expf(m - M2) : 0.f;
  float wo = (om > NEG) ? __expf(om - M2) : 0.f;
  l = l * wsc + ol * wo;
#pragma unroll
  for (int j = 0; j < 8; ++j) {
    float oa = __shfl_xor(a[j], 32);
    a[j] = a[j] * wsc + oa * wo;
  }
  float M = fmaxf(M2, 0.f);
  float em = (M2 > NEG) ? __expf(M2 - M) : 0.f;
  float denom = fmaxf(l * em, 1e-8f);
  float f = em / denom;
  if (half == 0) {
    u16x8 o;
#pragma unroll
    for (int j = 0; j < 8; ++j) o[j] = f2b(a[j] * f);
    *(u16x8*)(attn_b + (size_t)q * DN + d0) = o;
  }
}

extern "C" void kernel_launch(void* const* d_in, const int* in_sizes, int n_in,
                              void* d_out, int out_size, void* d_ws, size_t ws_size,
                              hipStream_t stream) {
  const float* query_tokens  = (const float*)d_in[0];
  const float* query_pos     = (const float*)d_in[1];
  const float* support_feats = (const float*)d_in[2];
  const float* support_pos   = (const float*)d_in[3];
  const float* Wq  = (const float*)d_in[4];
  const float* Wk  = (const float*)d_in[5];
  const float* Wv  = (const float*)d_in[6];
  const float* Wg  = (const float*)d_in[7];
  const float* Wo  = (const float*)d_in[8];
  const float* bo  = (const float*)d_in[9];
  const float* log_tau = (const float*)d_in[10];
  const float* ln1_g = (const float*)d_in[11];
  const float* ln1_b = (const float*)d_in[12];
  const float* ln2_g = (const float*)d_in[13];
  const float* ln2_b = (const float*)d_in[14];
  const float* Wf1 = (const float*)d_in[15];
  const float* bf1 = (const float*)d_in[16];
  const float* Wf2 = (const float*)d_in[17];
  const float* bf2 = (const float*)d_in[18];
  const float* Gw1 = (const float*)d_in[19];
  const float* Gb1 = (const float*)d_in[20];
  const float* Gw2 = (const float*)d_in[21];
  const float* Gb2 = (const float*)d_in[22];
  const int* q_idx = (const int*)d_in[23];
  const int* s_idx = (const int*)d_in[24];
  float* out = (float*)d_out;

  char* ws = (char*)d_ws;
  size_t off = 0;
  auto alloc = [&](size_t bytes) -> void* {
    void* p = ws + off;
    off = (off + bytes + 255) & ~(size_t)255;
    return p;
  };
  unsigned short* WqT  = (unsigned short*)alloc(65536 * 2);
  unsigned short* WkvT = (unsigned short*)alloc(131072 * 2);
  unsigned short* WgT  = (unsigned short*)alloc(32768 * 2);
  unsigned short* WoT  = (unsigned short*)alloc(65536 * 2);
  unsigned short* Wf1T = (unsigned short*)alloc(131072 * 2);
  unsigned short* Wf2T = (unsigned short*)alloc(131072 * 2);
  int* offs            = (int*)alloc((QN + 1) * 4);
  float* raw           = (float*)alloc((size_t)QN * 12 * 4);
  unsigned short* geo_b = (unsigned short*)alloc((size_t)QN * GEON * 2);
  unsigned short* qt_b  = (unsigned short*)alloc((size_t)QN * DN * 2);
  unsigned short* Qb    = (unsigned short*)alloc((size_t)QN * DN * 2);
  unsigned short* Gf_b  = (unsigned short*)alloc((size_t)QN * DN * 2);
  unsigned short* KVb   = (unsigned short*)alloc((size_t)SN * 512 * 2);
  unsigned short* attn_b = (unsigned short*)alloc((size_t)QN * DN * 2);
  float* x1             = (float*)alloc((size_t)QN * DN * 4);
  unsigned short* z_b   = (unsigned short*)alloc((size_t)QN * DN * 2);
  unsigned short* h_b   = (unsigned short*)alloc((size_t)QN * FFNN * 2);

  // 1. prep: weight transpose | segment offsets | LN1
  prep_kernel<<<TRB + SOB + QN / 4, 256, 0, stream>>>(
      Wq, Wk, Wv, Wg, Wo, Wf1, Wf2, WqT, WkvT, WgT, WoT, Wf1T, Wf2T,
      q_idx, offs, query_tokens, ln1_g, ln1_b, qt_b);
  // 2. geo stats
  geo_stats_kernel<<<QN / 64, 256, 0, stream>>>(query_pos, support_pos, offs, s_idx, raw);
  // 3. geo MLP (fused, shuffle-based)
  geo_mlp_kernel<<<QN / 4, 256, 0, stream>>>(raw, Gw1, Gb1, Gw2, Gb2, geo_b);
  // 4. KV = support_feats @ [Wk|Wv] — gemm128 (padded), 1024 blocks = 4/CU
  gemm128<true, false, false, false, false><<<dim3(SN / 128, 512 / 128), 256, 0, stream>>>(
      support_feats, WkvT, SN, 512, 256, nullptr, nullptr, nullptr, KVb);
  // 5. Qf | Gf fused
  qg_gemm<<<dim3(QN / 64, 8), 256, 0, stream>>>(qt_b, WqT, geo_b, WgT, Qb, Gf_b);
  // 6. edge attention
  attn_edge_kernel<<<QN / 4, 256, 0, stream>>>(Qb, Gf_b, KVb, s_idx, offs, log_tau, attn_b);
  // 7. x1 = attn @ Wo + bo + query_tokens
  gemm64<true, false, true, true><<<dim3(QN / 64, DN / 64), 256, 0, stream>>>(
      attn_b, WoT, QN, DN, 256, bo, query_tokens, x1, nullptr);
  // 8. LN2
  ln_kernel<<<QN / 4, 256, 0, stream>>>(x1, ln2_g, ln2_b, z_b);
  // 9. h = gelu(z @ Wf1 + bf1) — back to gemm64 (512 blocks = 2/CU)
  gemm64<true, true, false, false><<<dim3(QN / 64, FFNN / 64), 256, 0, stream>>>(
      z_b, Wf1T, QN, FFNN, 256, bf1, nullptr, nullptr, h_b);
  // 10. out = h @ Wf2 + bf2 + x1
  gemm64<true, false, true, true><<<dim3(QN / 64, DN / 64), 256, 0, stream>>>(
      h_b, Wf2T, QN, DN, 512, bf2, x1, out, nullptr);

  (void)in_sizes; (void)n_in; (void)out_size; (void)ws_size;
}